// Round 9
// baseline (5051.517 us; speedup 1.0000x reference)
//
#include <hip/hip_runtime.h>
#include <math.h>
#include <stdint.h>

#define B 64
#define S 512
#define DIN 768
#define H 64
#define G4 256   // 4*H gates per direction
#define NG 512   // 2 directions * 4H
#define DM 128   // bidirectional output width

typedef _Float16 h2_t __attribute__((ext_vector_type(2)));
typedef _Float16 f16x8 __attribute__((ext_vector_type(8)));
typedef float f32x4 __attribute__((ext_vector_type(4)));

#if defined(__has_builtin)
#if __has_builtin(__builtin_amdgcn_fdot2)
#define HAS_FDOT2 1
#endif
#endif

__device__ __forceinline__ h2_t u2h(uint32_t u) {
    h2_t h;
    __builtin_memcpy(&h, &u, 4);
    return h;
}

__device__ __forceinline__ float dot2f(h2_t a, h2_t b, float acc) {
#ifdef HAS_FDOT2
    return __builtin_amdgcn_fdot2(a, b, acc, false);
#else
    acc = fmaf((float)a.x, (float)b.x, acc);
    return fmaf((float)a.y, (float)b.y, acc);
#endif
}

__device__ __forceinline__ float sigm(float x) {
    return 1.0f / (1.0f + __expf(-x));
}
__device__ __forceinline__ float tanh_fast(float x) {
    return 1.0f - 2.0f / (__expf(2.0f * x) + 1.0f);
}

// ---------------------------------------------------------------------------
// Pooling: word_ids are sorted per row -> run-length accumulate, no atomics.
// ---------------------------------------------------------------------------
__global__ void pool_kernel(const float* __restrict__ emb,
                            const int* __restrict__ ids,
                            float* __restrict__ merged) {
    int b = blockIdx.x;
    int d = blockIdx.y * 128 + threadIdx.x;
    __shared__ int ids_s[S];
    for (int i = threadIdx.x; i < S; i += blockDim.x) ids_s[i] = ids[b * S + i];
    __syncthreads();
    const float* eb = emb + (size_t)b * S * DIN + d;
    float* mb = merged + (size_t)b * S * DIN + d;
    float acc = 0.f;
    for (int s = 0; s < S; ++s) {
        acc += eb[(size_t)s * DIN];
        int id = ids_s[s];
        bool flush = (s == S - 1) || (ids_s[s + 1] != id);
        if (flush) {
            mb[(size_t)id * DIN] = acc;
            acc = 0.f;
        }
    }
}

// ---------------------------------------------------------------------------
// Mask: one 64-lane wave per (b,word) row; mask = (sum over 768 != 0)
// ---------------------------------------------------------------------------
__global__ void mask_kernel(const float* __restrict__ merged,
                            float* __restrict__ mask) {
    int row = blockIdx.x * 4 + (threadIdx.x >> 6);
    int lane = threadIdx.x & 63;
    const float* r = merged + (size_t)row * DIN;
    float s = 0.f;
    #pragma unroll
    for (int i = 0; i < DIN / 64; ++i) s += r[lane + i * 64];
    #pragma unroll
    for (int off = 32; off > 0; off >>= 1) s += __shfl_down(s, off);
    if (lane == 0) mask[row] = (s != 0.f) ? 1.0f : 0.0f;
}

// ---------------------------------------------------------------------------
// MFMA GEMM: C[m][n] = sum_k A[m][k]*Wt[n][k] + bias[n], via f16 MFMA.
// ---------------------------------------------------------------------------
#define LDK 40

__global__ __launch_bounds__(256, 2) void gemm_mfma(
    const float* __restrict__ A, int K,
    const float* __restrict__ Wt, const float* __restrict__ bias,
    float* __restrict__ C) {
    __shared__ __align__(16) _Float16 Alds[128][LDK];
    __shared__ __align__(16) _Float16 Blds[64][LDK];
    int tid = threadIdx.x;
    int lane = tid & 63;
    int wave = tid >> 6;
    int wm = wave >> 1, wn = wave & 1;
    int n0 = blockIdx.x * 64;
    int m0 = blockIdx.y * 128;

    int tr = tid >> 2;            // staging row 0..63
    int tc = (tid & 3) << 3;      // staging k-chunk (8 floats)

    f32x4 acc[4][2] = {};

    const float* Ab = A + (size_t)m0 * K;
    for (int k0 = 0; k0 < K; k0 += 32) {
        {
            const float* src = Ab + (size_t)tr * K + k0 + tc;
            float4 v0 = *(const float4*)(src);
            float4 v1 = *(const float4*)(src + 4);
            _Float16* dst = &Alds[tr][tc];
            dst[0] = (_Float16)v0.x; dst[1] = (_Float16)v0.y;
            dst[2] = (_Float16)v0.z; dst[3] = (_Float16)v0.w;
            dst[4] = (_Float16)v1.x; dst[5] = (_Float16)v1.y;
            dst[6] = (_Float16)v1.z; dst[7] = (_Float16)v1.w;
            src += (size_t)64 * K;
            float4 v2 = *(const float4*)(src);
            float4 v3 = *(const float4*)(src + 4);
            dst = &Alds[tr + 64][tc];
            dst[0] = (_Float16)v2.x; dst[1] = (_Float16)v2.y;
            dst[2] = (_Float16)v2.z; dst[3] = (_Float16)v2.w;
            dst[4] = (_Float16)v3.x; dst[5] = (_Float16)v3.y;
            dst[6] = (_Float16)v3.z; dst[7] = (_Float16)v3.w;
        }
        {
            const float* src = Wt + (size_t)(n0 + tr) * K + k0 + tc;
            float4 v0 = *(const float4*)(src);
            float4 v1 = *(const float4*)(src + 4);
            _Float16* dst = &Blds[tr][tc];
            dst[0] = (_Float16)v0.x; dst[1] = (_Float16)v0.y;
            dst[2] = (_Float16)v0.z; dst[3] = (_Float16)v0.w;
            dst[4] = (_Float16)v1.x; dst[5] = (_Float16)v1.y;
            dst[6] = (_Float16)v1.z; dst[7] = (_Float16)v1.w;
        }
        __syncthreads();

        int fr = lane & 15;
        int kg = (lane >> 4) << 3;
        f16x8 af[4], bf[2];
        #pragma unroll
        for (int mf = 0; mf < 4; ++mf)
            af[mf] = *(const f16x8*)&Alds[wm * 64 + mf * 16 + fr][kg];
        #pragma unroll
        for (int nf = 0; nf < 2; ++nf)
            bf[nf] = *(const f16x8*)&Blds[wn * 32 + nf * 16 + fr][kg];
        #pragma unroll
        for (int mf = 0; mf < 4; ++mf)
            #pragma unroll
            for (int nf = 0; nf < 2; ++nf)
                acc[mf][nf] = __builtin_amdgcn_mfma_f32_16x16x32_f16(
                    af[mf], bf[nf], acc[mf][nf], 0, 0, 0);
        __syncthreads();
    }

    int col = lane & 15;
    int r4 = (lane >> 4) << 2;
    #pragma unroll
    for (int nf = 0; nf < 2; ++nf) {
        int n = n0 + wn * 32 + nf * 16 + col;
        float bv = bias[n];
        #pragma unroll
        for (int mf = 0; mf < 4; ++mf) {
            #pragma unroll
            for (int reg = 0; reg < 4; ++reg) {
                int m = m0 + wm * 64 + mf * 16 + r4 + reg;
                C[(size_t)m * NG + n] = acc[mf][nf][reg] + bv;
            }
        }
    }
}

// ---------------------------------------------------------------------------
// Recurrence: ONE WAVE runs TWO batch chains (same dir, shared f16 W_hh in
// 64 VGPRs). Two independent dep chains interleave in the issue slots to
// hide VALU latency (single wave/SIMD exposes ~4cy/op otherwise).
// R7-proven ordering: broadcast ds_reads at top of step, write at bottom.
// Zero barriers (same-wave DS ordering).
// ---------------------------------------------------------------------------
__global__ __launch_bounds__(64, 1) void lstm_rec(
    const float* __restrict__ pre,   // [B*S][512]
    const float* __restrict__ Whh,   // [512][64] (dir*256+g rows)
    const float* __restrict__ xin,   // [B*S][128] or nullptr
    float* __restrict__ xout,        // [B*S][128]
    int residual) {
    int pair = blockIdx.x >> 1;
    int dir = blockIdx.x & 1;
    int bA = pair * 2, bB = bA + 1;
    int j = threadIdx.x & 63;

    h2_t wg0[32], wg1[32], wg2[32], wg3[32];
    {
        const float* w0 = Whh + (size_t)(dir * G4 + 0 * H + j) * H;
        const float* w1 = Whh + (size_t)(dir * G4 + 1 * H + j) * H;
        const float* w2 = Whh + (size_t)(dir * G4 + 2 * H + j) * H;
        const float* w3 = Whh + (size_t)(dir * G4 + 3 * H + j) * H;
        #pragma unroll
        for (int kk = 0; kk < 32; ++kk) {
            float2 v;
            h2_t p;
            v = *(const float2*)&w0[kk * 2];
            p.x = (_Float16)v.x; p.y = (_Float16)v.y; wg0[kk] = p;
            v = *(const float2*)&w1[kk * 2];
            p.x = (_Float16)v.x; p.y = (_Float16)v.y; wg1[kk] = p;
            v = *(const float2*)&w2[kk * 2];
            p.x = (_Float16)v.x; p.y = (_Float16)v.y; wg2[kk] = p;
            v = *(const float2*)&w3[kk * 2];
            p.x = (_Float16)v.x; p.y = (_Float16)v.y; wg3[kk] = p;
        }
    }

    const float* prebA = pre + (size_t)bA * S * NG + dir * G4 + j;
    const float* prebB = pre + (size_t)bB * S * NG + dir * G4 + j;
    const float* xinbA = xin + (size_t)bA * S * DM + dir * H + j;
    const float* xinbB = xin + (size_t)bB * S * DM + dir * H + j;
    float* xoutbA = xout + (size_t)bA * S * DM + dir * H + j;
    float* xoutbB = xout + (size_t)bB * S * DM + dir * H + j;

    // 2-deep prefetch per chain (10 regs/chain) to bound register pressure;
    // 2 steps ~ 2200cy > 900cy HBM latency.
    float piA[2], pfA[2], pgA[2], poA[2], rbA[2] = {0.f, 0.f};
    float piB[2], pfB[2], pgB[2], poB[2], rbB[2] = {0.f, 0.f};
    #pragma unroll
    for (int i = 0; i < 2; ++i) {
        int s = dir ? (S - 1 - i) : i;
        const float* pA = prebA + (size_t)s * NG;
        const float* pB = prebB + (size_t)s * NG;
        piA[i] = pA[0]; pfA[i] = pA[64]; pgA[i] = pA[128]; poA[i] = pA[192];
        piB[i] = pB[0]; pfB[i] = pB[64]; pgB[i] = pB[128]; poB[i] = pB[192];
        if (residual) {
            rbA[i] = xinbA[(size_t)s * DM];
            rbB[i] = xinbB[(size_t)s * DM];
        }
    }

    __shared__ __align__(16) _Float16 shh[128];   // [2][64]
    const uint4* hpA = (const uint4*)&shh[0];
    const uint4* hpB = (const uint4*)&shh[64];
    shh[j] = (_Float16)0.f;
    shh[64 + j] = (_Float16)0.f;

    float cA = 0.f, cB = 0.f;
    #pragma unroll 2
    for (int step = 0; step < S; ++step) {
        int s = dir ? (S - 1 - step) : step;
        int q = step & 1;

        // ---- broadcast-read both h vectors (16 x ds_read_b128, uniform)
        uint4 hqA[8], hqB[8];
        #pragma unroll
        for (int r = 0; r < 8; ++r) { hqA[r] = hpA[r]; hqB[r] = hpB[r]; }

        // ---- dots: two independent chains interleaved
        float aiA = piA[q], afA = pfA[q], agA = pgA[q], aoA = poA[q];
        float aiB = piB[q], afB = pfB[q], agB = pgB[q], aoB = poB[q];
        #pragma unroll
        for (int r = 0; r < 8; ++r) {
            uint32_t uA[4] = {hqA[r].x, hqA[r].y, hqA[r].z, hqA[r].w};
            uint32_t uB[4] = {hqB[r].x, hqB[r].y, hqB[r].z, hqB[r].w};
            #pragma unroll
            for (int cc = 0; cc < 4; ++cc) {
                int kk = r * 4 + cc;
                h2_t hA = u2h(uA[cc]);
                h2_t hB = u2h(uB[cc]);
                aiA = dot2f(hA, wg0[kk], aiA);
                aiB = dot2f(hB, wg0[kk], aiB);
                afA = dot2f(hA, wg1[kk], afA);
                afB = dot2f(hB, wg1[kk], afB);
                agA = dot2f(hA, wg2[kk], agA);
                agB = dot2f(hB, wg2[kk], agB);
                aoA = dot2f(hA, wg3[kk], aoA);
                aoB = dot2f(hB, wg3[kk], aoB);
            }
        }

        // ---- activations (two independent chains)
        cA = sigm(afA) * cA + sigm(aiA) * tanh_fast(agA);
        cB = sigm(afB) * cB + sigm(aiB) * tanh_fast(agB);
        float hA = sigm(aoA) * tanh_fast(cA);
        float hB = sigm(aoB) * tanh_fast(cB);

        // ---- publish h (read at top of next step)
        shh[j] = (_Float16)hA;
        shh[64 + j] = (_Float16)hB;

        // ---- store + prefetch tail
        float rvA = rbA[q], rvB = rbB[q];
        int sn = step + 2;
        if (sn < S) {
            int s2 = dir ? (S - 1 - sn) : sn;
            const float* pA = prebA + (size_t)s2 * NG;
            const float* pB = prebB + (size_t)s2 * NG;
            piA[q] = pA[0]; pfA[q] = pA[64]; pgA[q] = pA[128]; poA[q] = pA[192];
            piB[q] = pB[0]; pfB[q] = pB[64]; pgB[q] = pB[128]; poB[q] = pB[192];
            if (residual) {
                rbA[q] = xinbA[(size_t)s2 * DM];
                rbB[q] = xinbB[(size_t)s2 * DM];
            }
        }
        xoutbA[(size_t)s * DM] = hA + rvA;
        xoutbB[(size_t)s * DM] = hB + rvB;
    }
}

// ---------------------------------------------------------------------------
// Assemble: out0[b,s,0:128] = x, out0[b,s,128] = sn_word_len[b,s]
// ---------------------------------------------------------------------------
__global__ void assemble_kernel(const float* __restrict__ x,
                                const float* __restrict__ wl,
                                float* __restrict__ out0) {
    int idx = blockIdx.x * blockDim.x + threadIdx.x;
    if (idx >= B * S * 129) return;
    int c = idx % 129;
    int bs = idx / 129;
    out0[idx] = (c < 128) ? x[(size_t)bs * DM + c] : wl[bs];
}

extern "C" void kernel_launch(void* const* d_in, const int* in_sizes, int n_in,
                              void* d_out, int out_size, void* d_ws, size_t ws_size,
                              hipStream_t stream) {
    const float* emb  = (const float*)d_in[0];
    const float* wl   = (const float*)d_in[1];
    const float* Wih1 = (const float*)d_in[2];  // [512][768]
    const float* Whh1 = (const float*)d_in[3];  // [512][64]
    const float* b1   = (const float*)d_in[4];  // [512]
    const float* Wih  = (const float*)d_in[5];  // [7][512][128]
    const float* Whh  = (const float*)d_in[6];  // [7][512][64]
    const float* bb   = (const float*)d_in[7];  // [7][512]
    const int*   ids  = (const int*)d_in[8];

    float* out0 = (float*)d_out;
    float* mask_out = out0 + (size_t)B * S * 129;

    float* merged = (float*)d_ws;                       // 25165824 f
    float* pre    = merged + (size_t)B * S * DIN;       // 16777216 f
    float* xA     = pre + (size_t)B * S * NG;           //  4194304 f
    float* xB     = xA + (size_t)B * S * DM;            //  4194304 f

    hipMemsetAsync(merged, 0, (size_t)B * S * DIN * sizeof(float), stream);
    pool_kernel<<<dim3(B, 6), 128, 0, stream>>>(emb, ids, merged);
    mask_kernel<<<(B * S) / 4, 256, 0, stream>>>(merged, mask_out);

    dim3 ggrid(NG / 64, (B * S) / 128);   // (8, 256), N fastest

    // layer 1: 768 -> 128
    gemm_mfma<<<ggrid, 256, 0, stream>>>(merged, DIN, Wih1, b1, pre);
    lstm_rec<<<B, 64, 0, stream>>>(pre, Whh1, nullptr, xA, 0);

    // layer 2: no residual
    gemm_mfma<<<ggrid, 256, 0, stream>>>(xA, DM, Wih, bb, pre);
    lstm_rec<<<B, 64, 0, stream>>>(pre, Whh, nullptr, xB, 0);

    // layers 3..8: residual
    float* cur = xB;
    float* oth = xA;
    for (int l = 1; l < 7; ++l) {
        gemm_mfma<<<ggrid, 256, 0, stream>>>(cur, DM, Wih + (size_t)l * NG * DM,
                                             bb + (size_t)l * NG, pre);
        lstm_rec<<<B, 64, 0, stream>>>(pre, Whh + (size_t)l * NG * H,
                                       cur, oth, 1);
        float* tmp = cur; cur = oth; oth = tmp;
    }
    // cur == xB after 6 swaps

    assemble_kernel<<<(B * S * 129 + 255) / 256, 256, 0, stream>>>(cur, wl, out0);
}

// Round 10
// 3660.312 us; speedup vs baseline: 1.3801x; 1.3801x over previous
//
#include <hip/hip_runtime.h>
#include <math.h>
#include <stdint.h>

#define B 64
#define S 512
#define DIN 768
#define H 64
#define G4 256   // 4*H gates per direction
#define NG 512   // 2 directions * 4H
#define DM 128   // bidirectional output width

typedef _Float16 h2_t __attribute__((ext_vector_type(2)));
typedef _Float16 f16x8 __attribute__((ext_vector_type(8)));
typedef float f32x4 __attribute__((ext_vector_type(4)));

__device__ __forceinline__ float sigm(float x) {
    return 1.0f / (1.0f + __expf(-x));
}
__device__ __forceinline__ float tanh_fast(float x) {
    return 1.0f - 2.0f / (__expf(2.0f * x) + 1.0f);
}

// ---------------------------------------------------------------------------
// Pooling: word_ids are sorted per row -> run-length accumulate, no atomics.
// ---------------------------------------------------------------------------
__global__ void pool_kernel(const float* __restrict__ emb,
                            const int* __restrict__ ids,
                            float* __restrict__ merged) {
    int b = blockIdx.x;
    int d = blockIdx.y * 128 + threadIdx.x;
    __shared__ int ids_s[S];
    for (int i = threadIdx.x; i < S; i += blockDim.x) ids_s[i] = ids[b * S + i];
    __syncthreads();
    const float* eb = emb + (size_t)b * S * DIN + d;
    float* mb = merged + (size_t)b * S * DIN + d;
    float acc = 0.f;
    for (int s = 0; s < S; ++s) {
        acc += eb[(size_t)s * DIN];
        int id = ids_s[s];
        bool flush = (s == S - 1) || (ids_s[s + 1] != id);
        if (flush) {
            mb[(size_t)id * DIN] = acc;
            acc = 0.f;
        }
    }
}

// ---------------------------------------------------------------------------
// Mask: one 64-lane wave per (b,word) row; mask = (sum over 768 != 0)
// ---------------------------------------------------------------------------
__global__ void mask_kernel(const float* __restrict__ merged,
                            float* __restrict__ mask) {
    int row = blockIdx.x * 4 + (threadIdx.x >> 6);
    int lane = threadIdx.x & 63;
    const float* r = merged + (size_t)row * DIN;
    float s = 0.f;
    #pragma unroll
    for (int i = 0; i < DIN / 64; ++i) s += r[lane + i * 64];
    #pragma unroll
    for (int off = 32; off > 0; off >>= 1) s += __shfl_down(s, off);
    if (lane == 0) mask[row] = (s != 0.f) ? 1.0f : 0.0f;
}

// ---------------------------------------------------------------------------
// MFMA GEMM: C[m][n] = sum_k A[m][k]*Wt[n][k] + bias[n], via f16 MFMA.
// ---------------------------------------------------------------------------
#define LDK 40

__global__ __launch_bounds__(256, 2) void gemm_mfma(
    const float* __restrict__ A, int K,
    const float* __restrict__ Wt, const float* __restrict__ bias,
    float* __restrict__ C) {
    __shared__ __align__(16) _Float16 Alds[128][LDK];
    __shared__ __align__(16) _Float16 Blds[64][LDK];
    int tid = threadIdx.x;
    int lane = tid & 63;
    int wave = tid >> 6;
    int wm = wave >> 1, wn = wave & 1;
    int n0 = blockIdx.x * 64;
    int m0 = blockIdx.y * 128;

    int tr = tid >> 2;            // staging row 0..63
    int tc = (tid & 3) << 3;      // staging k-chunk (8 floats)

    f32x4 acc[4][2] = {};

    const float* Ab = A + (size_t)m0 * K;
    for (int k0 = 0; k0 < K; k0 += 32) {
        {
            const float* src = Ab + (size_t)tr * K + k0 + tc;
            float4 v0 = *(const float4*)(src);
            float4 v1 = *(const float4*)(src + 4);
            _Float16* dst = &Alds[tr][tc];
            dst[0] = (_Float16)v0.x; dst[1] = (_Float16)v0.y;
            dst[2] = (_Float16)v0.z; dst[3] = (_Float16)v0.w;
            dst[4] = (_Float16)v1.x; dst[5] = (_Float16)v1.y;
            dst[6] = (_Float16)v1.z; dst[7] = (_Float16)v1.w;
            src += (size_t)64 * K;
            float4 v2 = *(const float4*)(src);
            float4 v3 = *(const float4*)(src + 4);
            dst = &Alds[tr + 64][tc];
            dst[0] = (_Float16)v2.x; dst[1] = (_Float16)v2.y;
            dst[2] = (_Float16)v2.z; dst[3] = (_Float16)v2.w;
            dst[4] = (_Float16)v3.x; dst[5] = (_Float16)v3.y;
            dst[6] = (_Float16)v3.z; dst[7] = (_Float16)v3.w;
        }
        {
            const float* src = Wt + (size_t)(n0 + tr) * K + k0 + tc;
            float4 v0 = *(const float4*)(src);
            float4 v1 = *(const float4*)(src + 4);
            _Float16* dst = &Blds[tr][tc];
            dst[0] = (_Float16)v0.x; dst[1] = (_Float16)v0.y;
            dst[2] = (_Float16)v0.z; dst[3] = (_Float16)v0.w;
            dst[4] = (_Float16)v1.x; dst[5] = (_Float16)v1.y;
            dst[6] = (_Float16)v1.z; dst[7] = (_Float16)v1.w;
        }
        __syncthreads();

        int fr = lane & 15;
        int kg = (lane >> 4) << 3;
        f16x8 af[4], bf[2];
        #pragma unroll
        for (int mf = 0; mf < 4; ++mf)
            af[mf] = *(const f16x8*)&Alds[wm * 64 + mf * 16 + fr][kg];
        #pragma unroll
        for (int nf = 0; nf < 2; ++nf)
            bf[nf] = *(const f16x8*)&Blds[wn * 32 + nf * 16 + fr][kg];
        #pragma unroll
        for (int mf = 0; mf < 4; ++mf)
            #pragma unroll
            for (int nf = 0; nf < 2; ++nf)
                acc[mf][nf] = __builtin_amdgcn_mfma_f32_16x16x32_f16(
                    af[mf], bf[nf], acc[mf][nf], 0, 0, 0);
        __syncthreads();
    }

    int col = lane & 15;
    int r4 = (lane >> 4) << 2;
    #pragma unroll
    for (int nf = 0; nf < 2; ++nf) {
        int n = n0 + wn * 32 + nf * 16 + col;
        float bv = bias[n];
        #pragma unroll
        for (int mf = 0; mf < 4; ++mf) {
            #pragma unroll
            for (int reg = 0; reg < 4; ++reg) {
                int m = m0 + wm * 64 + mf * 16 + r4 + reg;
                C[(size_t)m * NG + n] = acc[mf][nf][reg] + bv;
            }
        }
    }
}

// ---------------------------------------------------------------------------
// Recurrence via MFMA: one wave per (batch, direction), zero barriers.
// gates[256] = Whh[256x64] @ h[64] done as 16 N-tiles x 2 K-halves of
// mfma_f32_16x16x32_f16 (~150cy issue) instead of 128 v_dot2 (~1024cy,
// the R7-R9 bottleneck). Broadcast-A: every lane reads the SAME h[kg..kg+8]
// from LDS -> A[r][k]=h[k] for all rows -> every D row holds the true
// gates; lane j then owns unit j (col=j&15, tile-quad j>>4 selected by
// static 4-way cndmask). Weights preloaded as 32 f16x8 B-fragments
// (128 VGPRs). h republished as f16 via 1 ds_write_b16 (same-wave DS
// ordering, no barrier). f32 accumulation throughout -> same numerics
// as R7 (absmax ~7.8e-3).
// ---------------------------------------------------------------------------
__global__ __launch_bounds__(64, 1) void lstm_rec(
    const float* __restrict__ pre,   // [B*S][512]
    const float* __restrict__ Whh,   // [512][64] (dir*256+g rows)
    const float* __restrict__ xin,   // [B*S][128] or nullptr
    float* __restrict__ xout,        // [B*S][128]
    int residual) {
    int b = blockIdx.x >> 1;
    int dir = blockIdx.x & 1;
    int j = threadIdx.x & 63;
    int c15 = j & 15;
    int kg = (j >> 4) << 3;          // k-offset 0/8/16/24

    // B-fragments: bf[t][hh] = Whh[dir*256 + 16t + c15][32*hh + kg .. +8]
    f16x8 bf[16][2];
    {
        const float* wbase = Whh + (size_t)dir * G4 * H;
        #pragma unroll
        for (int t = 0; t < 16; ++t) {
            const float* row = wbase + (size_t)(16 * t + c15) * H;
            #pragma unroll
            for (int hh = 0; hh < 2; ++hh) {
                float4 v0 = *(const float4*)(row + hh * 32 + kg);
                float4 v1 = *(const float4*)(row + hh * 32 + kg + 4);
                f16x8 f;
                f[0] = (_Float16)v0.x; f[1] = (_Float16)v0.y;
                f[2] = (_Float16)v0.z; f[3] = (_Float16)v0.w;
                f[4] = (_Float16)v1.x; f[5] = (_Float16)v1.y;
                f[6] = (_Float16)v1.z; f[7] = (_Float16)v1.w;
                bf[t][hh] = f;
            }
        }
    }

    const float* preb = pre + (size_t)b * S * NG + dir * G4 + j;
    const float* xinb = xin + (size_t)b * S * DM + dir * H + j;
    float* xoutb = xout + (size_t)b * S * DM + dir * H + j;

    float pi[4], pf[4], pg_[4], po[4], rb[4] = {0.f, 0.f, 0.f, 0.f};
    #pragma unroll
    for (int i = 0; i < 4; ++i) {
        int s = dir ? (S - 1 - i) : i;
        const float* p = preb + (size_t)s * NG;
        pi[i] = p[0];
        pf[i] = p[64];
        pg_[i] = p[128];
        po[i] = p[192];
        if (residual) rb[i] = xinb[(size_t)s * DM];
    }

    __shared__ __align__(16) _Float16 shh[64];
    shh[j] = (_Float16)0.f;

    int tq = j >> 4;   // tile-quad for this lane's unit
    float c = 0.f;
    #pragma unroll 4
    for (int step = 0; step < S; ++step) {
        int s = dir ? (S - 1 - step) : step;
        int q = step & 3;

        // ---- A-fragments: broadcast h (2 x ds_read_b128, 4 distinct addrs)
        f16x8 af0 = *(const f16x8*)&shh[kg];
        f16x8 af1 = *(const f16x8*)&shh[32 + kg];

        // ---- 32 MFMA: acc[t] = gates[16t + col] replicated in all rows
        f32x4 acc[16] = {};
        #pragma unroll
        for (int t = 0; t < 16; ++t) {
            acc[t] = __builtin_amdgcn_mfma_f32_16x16x32_f16(af0, bf[t][0],
                                                            acc[t], 0, 0, 0);
            acc[t] = __builtin_amdgcn_mfma_f32_16x16x32_f16(af1, bf[t][1],
                                                            acc[t], 0, 0, 0);
        }

        // ---- static 4-way select: lane j's unit j = 16*tq + c15
        // i at tile tq, f at 4+tq, g at 8+tq, o at 12+tq (rows all equal)
        float gi = 0.f, gf = 0.f, gg = 0.f, go = 0.f;
        #pragma unroll
        for (int tt = 0; tt < 4; ++tt) {
            if (tq == tt) {
                gi = acc[tt][0];
                gf = acc[4 + tt][0];
                gg = acc[8 + tt][0];
                go = acc[12 + tt][0];
            }
        }
        gi += pi[q]; gf += pf[q]; gg += pg_[q]; go += po[q];

        // ---- activations (lane-local f32)
        c = sigm(gf) * c + sigm(gi) * tanh_fast(gg);
        float h = sigm(go) * tanh_fast(c);

        // ---- publish h for next step (same-wave DS ordering, no barrier)
        shh[j] = (_Float16)h;

        // ---- store + prefetch tail
        float rv = rb[q];
        int sn = step + 4;
        if (sn < S) {
            int s2 = dir ? (S - 1 - sn) : sn;
            const float* p = preb + (size_t)s2 * NG;
            pi[q] = p[0];
            pf[q] = p[64];
            pg_[q] = p[128];
            po[q] = p[192];
            if (residual) rb[q] = xinb[(size_t)s2 * DM];
        }
        xoutb[(size_t)s * DM] = h + rv;
    }
}

// ---------------------------------------------------------------------------
// Assemble: out0[b,s,0:128] = x, out0[b,s,128] = sn_word_len[b,s]
// ---------------------------------------------------------------------------
__global__ void assemble_kernel(const float* __restrict__ x,
                                const float* __restrict__ wl,
                                float* __restrict__ out0) {
    int idx = blockIdx.x * blockDim.x + threadIdx.x;
    if (idx >= B * S * 129) return;
    int c = idx % 129;
    int bs = idx / 129;
    out0[idx] = (c < 128) ? x[(size_t)bs * DM + c] : wl[bs];
}

extern "C" void kernel_launch(void* const* d_in, const int* in_sizes, int n_in,
                              void* d_out, int out_size, void* d_ws, size_t ws_size,
                              hipStream_t stream) {
    const float* emb  = (const float*)d_in[0];
    const float* wl   = (const float*)d_in[1];
    const float* Wih1 = (const float*)d_in[2];  // [512][768]
    const float* Whh1 = (const float*)d_in[3];  // [512][64]
    const float* b1   = (const float*)d_in[4];  // [512]
    const float* Wih  = (const float*)d_in[5];  // [7][512][128]
    const float* Whh  = (const float*)d_in[6];  // [7][512][64]
    const float* bb   = (const float*)d_in[7];  // [7][512]
    const int*   ids  = (const int*)d_in[8];

    float* out0 = (float*)d_out;
    float* mask_out = out0 + (size_t)B * S * 129;

    float* merged = (float*)d_ws;                       // 25165824 f
    float* pre    = merged + (size_t)B * S * DIN;       // 16777216 f
    float* xA     = pre + (size_t)B * S * NG;           //  4194304 f
    float* xB     = xA + (size_t)B * S * DM;            //  4194304 f

    hipMemsetAsync(merged, 0, (size_t)B * S * DIN * sizeof(float), stream);
    pool_kernel<<<dim3(B, 6), 128, 0, stream>>>(emb, ids, merged);
    mask_kernel<<<(B * S) / 4, 256, 0, stream>>>(merged, mask_out);

    dim3 ggrid(NG / 64, (B * S) / 128);   // (8, 256), N fastest

    // layer 1: 768 -> 128
    gemm_mfma<<<ggrid, 256, 0, stream>>>(merged, DIN, Wih1, b1, pre);
    lstm_rec<<<2 * B, 64, 0, stream>>>(pre, Whh1, nullptr, xA, 0);

    // layer 2: no residual
    gemm_mfma<<<ggrid, 256, 0, stream>>>(xA, DM, Wih, bb, pre);
    lstm_rec<<<2 * B, 64, 0, stream>>>(pre, Whh, nullptr, xB, 0);

    // layers 3..8: residual
    float* cur = xB;
    float* oth = xA;
    for (int l = 1; l < 7; ++l) {
        gemm_mfma<<<ggrid, 256, 0, stream>>>(cur, DM, Wih + (size_t)l * NG * DM,
                                             bb + (size_t)l * NG, pre);
        lstm_rec<<<2 * B, 64, 0, stream>>>(pre, Whh + (size_t)l * NG * H,
                                           cur, oth, 1);
        float* tmp = cur; cur = oth; oth = tmp;
    }
    // cur == xB after 6 swaps

    assemble_kernel<<<(B * S * 129 + 255) / 256, 256, 0, stream>>>(cur, wl, out0);
}

// Round 11
// 3044.410 us; speedup vs baseline: 1.6593x; 1.2023x over previous
//
#include <hip/hip_runtime.h>
#include <math.h>
#include <stdint.h>

#define B 64
#define S 512
#define DIN 768
#define H 64
#define G4 256   // 4*H gates per direction
#define NG 512   // 2 directions * 4H
#define DM 128   // bidirectional output width

typedef _Float16 h2_t __attribute__((ext_vector_type(2)));
typedef _Float16 f16x8 __attribute__((ext_vector_type(8)));
typedef float f32x4 __attribute__((ext_vector_type(4)));

__device__ __forceinline__ h2_t u2h(uint32_t u) {
    h2_t h;
    __builtin_memcpy(&h, &u, 4);
    return h;
}

__device__ __forceinline__ float sigm(float x) {
    return 1.0f / (1.0f + __expf(-x));
}
__device__ __forceinline__ float tanh_fast(float x) {
    return 1.0f - 2.0f / (__expf(2.0f * x) + 1.0f);
}

// ---------------------------------------------------------------------------
// Pooling: word_ids are sorted per row -> run-length accumulate, no atomics.
// ---------------------------------------------------------------------------
__global__ void pool_kernel(const float* __restrict__ emb,
                            const int* __restrict__ ids,
                            float* __restrict__ merged) {
    int b = blockIdx.x;
    int d = blockIdx.y * 128 + threadIdx.x;
    __shared__ int ids_s[S];
    for (int i = threadIdx.x; i < S; i += blockDim.x) ids_s[i] = ids[b * S + i];
    __syncthreads();
    const float* eb = emb + (size_t)b * S * DIN + d;
    float* mb = merged + (size_t)b * S * DIN + d;
    float acc = 0.f;
    for (int s = 0; s < S; ++s) {
        acc += eb[(size_t)s * DIN];
        int id = ids_s[s];
        bool flush = (s == S - 1) || (ids_s[s + 1] != id);
        if (flush) {
            mb[(size_t)id * DIN] = acc;
            acc = 0.f;
        }
    }
}

// ---------------------------------------------------------------------------
// Mask: one 64-lane wave per (b,word) row; mask = (sum over 768 != 0)
// ---------------------------------------------------------------------------
__global__ void mask_kernel(const float* __restrict__ merged,
                            float* __restrict__ mask) {
    int row = blockIdx.x * 4 + (threadIdx.x >> 6);
    int lane = threadIdx.x & 63;
    const float* r = merged + (size_t)row * DIN;
    float s = 0.f;
    #pragma unroll
    for (int i = 0; i < DIN / 64; ++i) s += r[lane + i * 64];
    #pragma unroll
    for (int off = 32; off > 0; off >>= 1) s += __shfl_down(s, off);
    if (lane == 0) mask[row] = (s != 0.f) ? 1.0f : 0.0f;
}

// ---------------------------------------------------------------------------
// MFMA GEMM: C[m][n] = sum_k A[m][k]*Wt[n][k] + bias[n], via f16 MFMA.
// ---------------------------------------------------------------------------
#define LDK 40

__global__ __launch_bounds__(256, 2) void gemm_mfma(
    const float* __restrict__ A, int K,
    const float* __restrict__ Wt, const float* __restrict__ bias,
    float* __restrict__ C) {
    __shared__ __align__(16) _Float16 Alds[128][LDK];
    __shared__ __align__(16) _Float16 Blds[64][LDK];
    int tid = threadIdx.x;
    int lane = tid & 63;
    int wave = tid >> 6;
    int wm = wave >> 1, wn = wave & 1;
    int n0 = blockIdx.x * 64;
    int m0 = blockIdx.y * 128;

    int tr = tid >> 2;            // staging row 0..63
    int tc = (tid & 3) << 3;      // staging k-chunk (8 floats)

    f32x4 acc[4][2] = {};

    const float* Ab = A + (size_t)m0 * K;
    for (int k0 = 0; k0 < K; k0 += 32) {
        {
            const float* src = Ab + (size_t)tr * K + k0 + tc;
            float4 v0 = *(const float4*)(src);
            float4 v1 = *(const float4*)(src + 4);
            _Float16* dst = &Alds[tr][tc];
            dst[0] = (_Float16)v0.x; dst[1] = (_Float16)v0.y;
            dst[2] = (_Float16)v0.z; dst[3] = (_Float16)v0.w;
            dst[4] = (_Float16)v1.x; dst[5] = (_Float16)v1.y;
            dst[6] = (_Float16)v1.z; dst[7] = (_Float16)v1.w;
            src += (size_t)64 * K;
            float4 v2 = *(const float4*)(src);
            float4 v3 = *(const float4*)(src + 4);
            dst = &Alds[tr + 64][tc];
            dst[0] = (_Float16)v2.x; dst[1] = (_Float16)v2.y;
            dst[2] = (_Float16)v2.z; dst[3] = (_Float16)v2.w;
            dst[4] = (_Float16)v3.x; dst[5] = (_Float16)v3.y;
            dst[6] = (_Float16)v3.z; dst[7] = (_Float16)v3.w;
        }
        {
            const float* src = Wt + (size_t)(n0 + tr) * K + k0 + tc;
            float4 v0 = *(const float4*)(src);
            float4 v1 = *(const float4*)(src + 4);
            _Float16* dst = &Blds[tr][tc];
            dst[0] = (_Float16)v0.x; dst[1] = (_Float16)v0.y;
            dst[2] = (_Float16)v0.z; dst[3] = (_Float16)v0.w;
            dst[4] = (_Float16)v1.x; dst[5] = (_Float16)v1.y;
            dst[6] = (_Float16)v1.z; dst[7] = (_Float16)v1.w;
        }
        __syncthreads();

        int fr = lane & 15;
        int kg = (lane >> 4) << 3;
        f16x8 af[4], bf[2];
        #pragma unroll
        for (int mf = 0; mf < 4; ++mf)
            af[mf] = *(const f16x8*)&Alds[wm * 64 + mf * 16 + fr][kg];
        #pragma unroll
        for (int nf = 0; nf < 2; ++nf)
            bf[nf] = *(const f16x8*)&Blds[wn * 32 + nf * 16 + fr][kg];
        #pragma unroll
        for (int mf = 0; mf < 4; ++mf)
            #pragma unroll
            for (int nf = 0; nf < 2; ++nf)
                acc[mf][nf] = __builtin_amdgcn_mfma_f32_16x16x32_f16(
                    af[mf], bf[nf], acc[mf][nf], 0, 0, 0);
        __syncthreads();
    }

    int col = lane & 15;
    int r4 = (lane >> 4) << 2;
    #pragma unroll
    for (int nf = 0; nf < 2; ++nf) {
        int n = n0 + wn * 32 + nf * 16 + col;
        float bv = bias[n];
        #pragma unroll
        for (int mf = 0; mf < 4; ++mf) {
            #pragma unroll
            for (int reg = 0; reg < 4; ++reg) {
                int m = m0 + wm * 64 + mf * 16 + r4 + reg;
                C[(size_t)m * NG + n] = acc[mf][nf][reg] + bv;
            }
        }
    }
}

// ---------------------------------------------------------------------------
// Recurrence: ONE WAVE per (batch, direction), zero barriers — exact R7
// structure (263us), but dot engine = v_pk_fma_f16 (full-rate, ~2cy) instead
// of v_dot2_f32_f16 (quarter-rate ~8cy, proven issue-bound via R9's linear
// scaling). f16 accumulation in TWO accs per gate (even/odd kk -> 16-add
// chains), combined in f32. Broadcast ds_reads at top of step (R7-proven),
// h republished as f16 at bottom (same-wave DS ordering).
// ---------------------------------------------------------------------------
__global__ __launch_bounds__(64, 1) void lstm_rec(
    const float* __restrict__ pre,   // [B*S][512]
    const float* __restrict__ Whh,   // [512][64] (dir*256+g rows)
    const float* __restrict__ xin,   // [B*S][128] or nullptr
    float* __restrict__ xout,        // [B*S][128]
    int residual) {
    int b = blockIdx.x >> 1;
    int dir = blockIdx.x & 1;
    int j = threadIdx.x & 63;

    h2_t wg0[32], wg1[32], wg2[32], wg3[32];
    {
        const float* w0 = Whh + (size_t)(dir * G4 + 0 * H + j) * H;
        const float* w1 = Whh + (size_t)(dir * G4 + 1 * H + j) * H;
        const float* w2 = Whh + (size_t)(dir * G4 + 2 * H + j) * H;
        const float* w3 = Whh + (size_t)(dir * G4 + 3 * H + j) * H;
        #pragma unroll
        for (int kk = 0; kk < 32; ++kk) {
            float2 v;
            h2_t p;
            v = *(const float2*)&w0[kk * 2];
            p.x = (_Float16)v.x; p.y = (_Float16)v.y; wg0[kk] = p;
            v = *(const float2*)&w1[kk * 2];
            p.x = (_Float16)v.x; p.y = (_Float16)v.y; wg1[kk] = p;
            v = *(const float2*)&w2[kk * 2];
            p.x = (_Float16)v.x; p.y = (_Float16)v.y; wg2[kk] = p;
            v = *(const float2*)&w3[kk * 2];
            p.x = (_Float16)v.x; p.y = (_Float16)v.y; wg3[kk] = p;
        }
    }

    const float* preb = pre + (size_t)b * S * NG + dir * G4 + j;
    const float* xinb = xin + (size_t)b * S * DM + dir * H + j;
    float* xoutb = xout + (size_t)b * S * DM + dir * H + j;

    float pi[4], pf[4], pg_[4], po[4], rb[4] = {0.f, 0.f, 0.f, 0.f};
    #pragma unroll
    for (int i = 0; i < 4; ++i) {
        int s = dir ? (S - 1 - i) : i;
        const float* p = preb + (size_t)s * NG;
        pi[i] = p[0];
        pf[i] = p[64];
        pg_[i] = p[128];
        po[i] = p[192];
        if (residual) rb[i] = xinb[(size_t)s * DM];
    }

    __shared__ __align__(16) _Float16 shh[64];
    shh[j] = (_Float16)0.f;

    float c = 0.f;
    #pragma unroll 4
    for (int step = 0; step < S; ++step) {
        int s = dir ? (S - 1 - step) : step;
        int q = step & 3;
        float rv = rb[q];

        // ---- broadcast-read all 64 h values (8 x ds_read_b128, uniform)
        uint4 hq[8];
        const uint4* hp = (const uint4*)shh;
        #pragma unroll
        for (int r = 0; r < 8; ++r) hq[r] = hp[r];

        // ---- packed-f16 dots: 2 accs/gate (even/odd kk), f32 combine
        h2_t aie = {0, 0}, aio = {0, 0}, afe = {0, 0}, afo = {0, 0};
        h2_t age = {0, 0}, ago = {0, 0}, aoe = {0, 0}, aoo = {0, 0};
        #pragma unroll
        for (int r = 0; r < 8; ++r) {
            uint32_t uu[4] = {hq[r].x, hq[r].y, hq[r].z, hq[r].w};
            #pragma unroll
            for (int cc = 0; cc < 4; ++cc) {
                int kk = r * 4 + cc;
                h2_t hh = u2h(uu[cc]);
                if (kk & 1) {
                    aio = hh * wg0[kk] + aio;
                    afo = hh * wg1[kk] + afo;
                    ago = hh * wg2[kk] + ago;
                    aoo = hh * wg3[kk] + aoo;
                } else {
                    aie = hh * wg0[kk] + aie;
                    afe = hh * wg1[kk] + afe;
                    age = hh * wg2[kk] + age;
                    aoe = hh * wg3[kk] + aoe;
                }
            }
        }
        float ai = pi[q] + (((float)aie.x + (float)aie.y) +
                            ((float)aio.x + (float)aio.y));
        float af = pf[q] + (((float)afe.x + (float)afe.y) +
                            ((float)afo.x + (float)afo.y));
        float ag = pg_[q] + (((float)age.x + (float)age.y) +
                             ((float)ago.x + (float)ago.y));
        float ao = po[q] + (((float)aoe.x + (float)aoe.y) +
                            ((float)aoo.x + (float)aoo.y));

        // ---- activations
        c = sigm(af) * c + sigm(ai) * tanh_fast(ag);
        float h = sigm(ao) * tanh_fast(c);

        // ---- publish h (read at top of next step; same-wave DS ordering)
        shh[j] = (_Float16)h;

        // ---- store + prefetch tail
        int sn = step + 4;
        if (sn < S) {
            int s2 = dir ? (S - 1 - sn) : sn;
            const float* p = preb + (size_t)s2 * NG;
            pi[q] = p[0];
            pf[q] = p[64];
            pg_[q] = p[128];
            po[q] = p[192];
            if (residual) rb[q] = xinb[(size_t)s2 * DM];
        }
        xoutb[(size_t)s * DM] = h + rv;
    }
}

// ---------------------------------------------------------------------------
// Assemble: out0[b,s,0:128] = x, out0[b,s,128] = sn_word_len[b,s]
// ---------------------------------------------------------------------------
__global__ void assemble_kernel(const float* __restrict__ x,
                                const float* __restrict__ wl,
                                float* __restrict__ out0) {
    int idx = blockIdx.x * blockDim.x + threadIdx.x;
    if (idx >= B * S * 129) return;
    int c = idx % 129;
    int bs = idx / 129;
    out0[idx] = (c < 128) ? x[(size_t)bs * DM + c] : wl[bs];
}

extern "C" void kernel_launch(void* const* d_in, const int* in_sizes, int n_in,
                              void* d_out, int out_size, void* d_ws, size_t ws_size,
                              hipStream_t stream) {
    const float* emb  = (const float*)d_in[0];
    const float* wl   = (const float*)d_in[1];
    const float* Wih1 = (const float*)d_in[2];  // [512][768]
    const float* Whh1 = (const float*)d_in[3];  // [512][64]
    const float* b1   = (const float*)d_in[4];  // [512]
    const float* Wih  = (const float*)d_in[5];  // [7][512][128]
    const float* Whh  = (const float*)d_in[6];  // [7][512][64]
    const float* bb   = (const float*)d_in[7];  // [7][512]
    const int*   ids  = (const int*)d_in[8];

    float* out0 = (float*)d_out;
    float* mask_out = out0 + (size_t)B * S * 129;

    float* merged = (float*)d_ws;                       // 25165824 f
    float* pre    = merged + (size_t)B * S * DIN;       // 16777216 f
    float* xA     = pre + (size_t)B * S * NG;           //  4194304 f
    float* xB     = xA + (size_t)B * S * DM;            //  4194304 f

    hipMemsetAsync(merged, 0, (size_t)B * S * DIN * sizeof(float), stream);
    pool_kernel<<<dim3(B, 6), 128, 0, stream>>>(emb, ids, merged);
    mask_kernel<<<(B * S) / 4, 256, 0, stream>>>(merged, mask_out);

    dim3 ggrid(NG / 64, (B * S) / 128);   // (8, 256), N fastest

    // layer 1: 768 -> 128
    gemm_mfma<<<ggrid, 256, 0, stream>>>(merged, DIN, Wih1, b1, pre);
    lstm_rec<<<2 * B, 64, 0, stream>>>(pre, Whh1, nullptr, xA, 0);

    // layer 2: no residual
    gemm_mfma<<<ggrid, 256, 0, stream>>>(xA, DM, Wih, bb, pre);
    lstm_rec<<<2 * B, 64, 0, stream>>>(pre, Whh, nullptr, xB, 0);

    // layers 3..8: residual
    float* cur = xB;
    float* oth = xA;
    for (int l = 1; l < 7; ++l) {
        gemm_mfma<<<ggrid, 256, 0, stream>>>(cur, DM, Wih + (size_t)l * NG * DM,
                                             bb + (size_t)l * NG, pre);
        lstm_rec<<<2 * B, 64, 0, stream>>>(pre, Whh + (size_t)l * NG * H,
                                           cur, oth, 1);
        float* tmp = cur; cur = oth; oth = tmp;
    }
    // cur == xB after 6 swaps

    assemble_kernel<<<(B * S * 129 + 255) / 256, 256, 0, stream>>>(cur, wl, out0);
}